// Round 10
// baseline (1570.920 us; speedup 1.0000x reference)
//
#include <hip/hip_runtime.h>
#include <hip/hip_bf16.h>

// GraphRNN, fp32 I/O (reference dtypes are float32).
// beta = (seq @ E) / rowsum(graph); agg = graph^T @ beta (per batch);
// Xpre = agg @ Wx + b; then 1024-step scan h = tanh(Xpre_m + h @ Wh).
// MFMA path: fp32 operands split into bf16 hi+lo (rel err ~2^-18).
// Scan history: R5 8w 1153us; R6 barrier/lookahead NEUTRAL; R7 shfl-ectomy
// 1073us (prev BEST); R8 16w worse (A-broadcast x2); R9 DPP-packed writes
// worse (+60us: serial-tail VALU + worse bank aliasing) -> reverted.
// Pipe tally R7: DS ~1400cy/step (reads 770 + writes 370 + conf 256),
// matrix 1242cy, step 2515cy -> barrier phase-lock serializes pipes; DS
// read cost scales with wave count (8KB h-broadcast per wave).
// R10: 4 waves x 64 cols, 1 wave/SIMD (launch_bounds(256,1)). Weights
// 256 regs -> AGPRs (unified file, ~512/wave budget at 1 wave/SIMD; no
// spill, verify via FETCH_SIZE). DS reads halve; matrix constant.

typedef unsigned short u16;
typedef unsigned int u32;
typedef __bf16 bf16_t;
typedef __bf16 bf16x8 __attribute__((ext_vector_type(8)));
typedef float f32x4 __attribute__((ext_vector_type(4)));
typedef unsigned short u16x8 __attribute__((ext_vector_type(8)));
typedef unsigned short u16x4 __attribute__((ext_vector_type(4)));

#define LDS_P 72   // LDS pitch (u16) for 64-wide tiles
#define HP    264  // h LDS pitch (u16) for the scan: 256 + 8 pad

struct HiLo { u16 hi, lo; };

__device__ __forceinline__ u16 f2bf(float f) {
  bf16_t h = (bf16_t)f;  // RNE
  return __builtin_bit_cast(u16, h);
}
__device__ __forceinline__ HiLo splitf(float v) {
  bf16_t h = (bf16_t)v;
  HiLo r;
  r.hi = __builtin_bit_cast(u16, h);
  r.lo = f2bf(v - (float)h);
  return r;
}
__device__ __forceinline__ float tanh_fast(float x) {
  float ax = fabsf(x);
  float e  = __expf(-2.0f * ax);
  float t  = __fdividef(1.0f - e, 1.0f + e);
  return copysignf(t, x);
}
// Barrier with LDS-only visibility (drains lgkmcnt, not vmcnt).
__device__ __forceinline__ void sync_lds_only() {
  __asm__ volatile("s_waitcnt lgkmcnt(0)\ns_barrier" ::: "memory");
}

// ---------------- K0: transpose + hi/lo split of E, Wx, Wh ------------------
__global__ void transpose_split3(const float* __restrict__ s0, u16* __restrict__ h0, u16* __restrict__ l0,
                                 const float* __restrict__ s1, u16* __restrict__ h1, u16* __restrict__ l1,
                                 const float* __restrict__ s2, u16* __restrict__ h2o, u16* __restrict__ l2o) {
  const int u = blockIdx.x, d = threadIdx.x;
  const float* s; u16 *dh, *dl;
  if (blockIdx.y == 0)      { s = s0; dh = h0;  dl = l0; }
  else if (blockIdx.y == 1) { s = s1; dh = h1;  dl = l1; }
  else                      { s = s2; dh = h2o; dl = l2o; }
  HiLo r = splitf(s[d * 256 + u]);
  dh[u * 256 + d] = r.hi;
  dl[u * 256 + d] = r.lo;
}

// ---------------- K1: rnorm[b,l] = 1 / max(sum_m graph[b,l,m], 1e-7) --------
__global__ void rowsum_norm(const float* __restrict__ graph, float* __restrict__ rnorm) {
  const int wave = threadIdx.x >> 6, lane = threadIdx.x & 63;
  const int row = blockIdx.x * 4 + wave;  // 0..8191
  const float* p = graph + (size_t)row * 1024 + lane * 16;
  float s = 0.f;
#pragma unroll
  for (int c = 0; c < 4; c++) {
    f32x4 v = *(const f32x4*)(p + c * 4);
#pragma unroll
    for (int j = 0; j < 4; j++) s += v[j];
  }
#pragma unroll
  for (int off = 32; off > 0; off >>= 1) s += __shfl_xor(s, off);
  if (lane == 0) rnorm[row] = 1.0f / fmaxf(s, 1e-7f);
}

// ---------------- K2: betaT[b][u][l] hi/lo = (seq@E)[b,l,u] * rnorm[b,l] ----
__global__ __launch_bounds__(256, 2) void gemm_beta(const float* __restrict__ seq,
                                                    const u16* __restrict__ Eth,
                                                    const u16* __restrict__ Etl,
                                                    const float* __restrict__ rnorm,
                                                    u16* __restrict__ betaTh,
                                                    u16* __restrict__ betaTl) {
  __shared__ u16 Ah[64 * LDS_P], Al[64 * LDS_P];
  __shared__ u16 Bh[64 * LDS_P], Bl[64 * LDS_P];
  const int t = threadIdx.x;
  const int wave = t >> 6, lane = t & 63, quad = lane >> 4, l16 = lane & 15;
  const int r0 = blockIdx.x * 64, n0 = blockIdx.y * 64;
  f32x4 acc[4];
#pragma unroll
  for (int i = 0; i < 4; i++) acc[i] = (f32x4){0.f, 0.f, 0.f, 0.f};

  for (int kb = 0; kb < 256; kb += 64) {
#pragma unroll
    for (int cc = 0; cc < 4; cc++) {
      int c = t + cc * 256;
      int r = c >> 4, c4 = c & 15;
      f32x4 v = *(const f32x4*)(seq + (size_t)(r0 + r) * 256 + kb + c4 * 4);
      u16x4 hi, lo;
#pragma unroll
      for (int j = 0; j < 4; j++) {
        HiLo s = splitf(v[j]);
        hi[j] = s.hi; lo[j] = s.lo;
      }
      *(u16x4*)(Ah + r * LDS_P + c4 * 4) = hi;
      *(u16x4*)(Al + r * LDS_P + c4 * 4) = lo;
    }
#pragma unroll
    for (int cc = 0; cc < 2; cc++) {
      int c = t + cc * 256;
      int r = c >> 3, c8 = c & 7;
      *(u16x8*)(Bh + r * LDS_P + c8 * 8) =
          *(const u16x8*)(Eth + (size_t)(n0 + r) * 256 + kb + c8 * 8);
      *(u16x8*)(Bl + r * LDS_P + c8 * 8) =
          *(const u16x8*)(Etl + (size_t)(n0 + r) * 256 + kb + c8 * 8);
    }
    __syncthreads();
#pragma unroll
    for (int kk = 0; kk < 64; kk += 32) {
      bf16x8 ah = __builtin_bit_cast(bf16x8, *(const u16x8*)(Ah + (wave * 16 + l16) * LDS_P + kk + quad * 8));
      bf16x8 al = __builtin_bit_cast(bf16x8, *(const u16x8*)(Al + (wave * 16 + l16) * LDS_P + kk + quad * 8));
#pragma unroll
      for (int tN = 0; tN < 4; tN++) {
        bf16x8 bh = __builtin_bit_cast(bf16x8, *(const u16x8*)(Bh + (tN * 16 + l16) * LDS_P + kk + quad * 8));
        bf16x8 bl = __builtin_bit_cast(bf16x8, *(const u16x8*)(Bl + (tN * 16 + l16) * LDS_P + kk + quad * 8));
        acc[tN] = __builtin_amdgcn_mfma_f32_16x16x32_bf16(ah, bh, acc[tN], 0, 0, 0);
        acc[tN] = __builtin_amdgcn_mfma_f32_16x16x32_bf16(ah, bl, acc[tN], 0, 0, 0);
        acc[tN] = __builtin_amdgcn_mfma_f32_16x16x32_bf16(al, bh, acc[tN], 0, 0, 0);
      }
    }
    __syncthreads();
  }
  const int rbase = r0 + wave * 16 + quad * 4;  // b*1024 + l, 4 consecutive l
  float rn[4];
#pragma unroll
  for (int i = 0; i < 4; i++) rn[i] = rnorm[rbase + i];
  const int bI = rbase >> 10, lI = rbase & 1023;
#pragma unroll
  for (int tN = 0; tN < 4; tN++) {
    int u = n0 + tN * 16 + l16;
    u16x4 hv, lv;
#pragma unroll
    for (int i = 0; i < 4; i++) {
      HiLo s = splitf(acc[tN][i] * rn[i]);
      hv[i] = s.hi; lv[i] = s.lo;
    }
    size_t off = ((size_t)bI << 18) + (size_t)u * 1024 + lI;
    *(u16x4*)(betaTh + off) = hv;
    *(u16x4*)(betaTl + off) = lv;
  }
}

// ---------------- K3: agg[b][m][u] = sum_l graph[b][l][m] * beta[b][l][u] ---
__global__ __launch_bounds__(256, 2) void gemm_agg(const float* __restrict__ graph,
                                                   const u16* __restrict__ betaTh,
                                                   const u16* __restrict__ betaTl,
                                                   float* __restrict__ agg) {
  __shared__ u16 Ah[64 * LDS_P], Al[64 * LDS_P];
  __shared__ u16 Bh[64 * LDS_P], Bl[64 * LDS_P];
  const int t = threadIdx.x;
  const int wave = t >> 6, lane = t & 63, quad = lane >> 4, l16 = lane & 15;
  const int m0 = blockIdx.x * 64, n0 = blockIdx.y * 64, b = blockIdx.z;
  const float* g = graph + (size_t)b * (1024 * 1024);
  const size_t bt = (size_t)b << 18;
  f32x4 acc[4];
#pragma unroll
  for (int i = 0; i < 4; i++) acc[i] = (f32x4){0.f, 0.f, 0.f, 0.f};

  for (int kb = 0; kb < 1024; kb += 64) {
#pragma unroll
    for (int cc = 0; cc < 4; cc++) {
      int c = t + cc * 256;
      int r = c >> 4, c4 = c & 15;  // r = l_local, c4 = m-chunk of 4
      f32x4 v = *(const f32x4*)(g + (size_t)(kb + r) * 1024 + m0 + c4 * 4);
#pragma unroll
      for (int j = 0; j < 4; j++) {
        HiLo s = splitf(v[j]);
        Ah[(c4 * 4 + j) * LDS_P + r] = s.hi;  // A[m][l] = graph[l][m]
        Al[(c4 * 4 + j) * LDS_P + r] = s.lo;
      }
    }
#pragma unroll
    for (int cc = 0; cc < 2; cc++) {
      int c = t + cc * 256;
      int r = c >> 3, c8 = c & 7;
      *(u16x8*)(Bh + r * LDS_P + c8 * 8) =
          *(const u16x8*)(betaTh + bt + (size_t)(n0 + r) * 1024 + kb + c8 * 8);
      *(u16x8*)(Bl + r * LDS_P + c8 * 8) =
          *(const u16x8*)(betaTl + bt + (size_t)(n0 + r) * 1024 + kb + c8 * 8);
    }
    __syncthreads();
#pragma unroll
    for (int kk = 0; kk < 64; kk += 32) {
      bf16x8 ah = __builtin_bit_cast(bf16x8, *(const u16x8*)(Ah + (wave * 16 + l16) * LDS_P + kk + quad * 8));
      bf16x8 al = __builtin_bit_cast(bf16x8, *(const u16x8*)(Al + (wave * 16 + l16) * LDS_P + kk + quad * 8));
#pragma unroll
      for (int tN = 0; tN < 4; tN++) {
        bf16x8 bh = __builtin_bit_cast(bf16x8, *(const u16x8*)(Bh + (tN * 16 + l16) * LDS_P + kk + quad * 8));
        bf16x8 bl = __builtin_bit_cast(bf16x8, *(const u16x8*)(Bl + (tN * 16 + l16) * LDS_P + kk + quad * 8));
        acc[tN] = __builtin_amdgcn_mfma_f32_16x16x32_bf16(ah, bh, acc[tN], 0, 0, 0);
        acc[tN] = __builtin_amdgcn_mfma_f32_16x16x32_bf16(ah, bl, acc[tN], 0, 0, 0);
        acc[tN] = __builtin_amdgcn_mfma_f32_16x16x32_bf16(al, bh, acc[tN], 0, 0, 0);
      }
    }
    __syncthreads();
  }
  const int mbase = m0 + wave * 16 + quad * 4;
#pragma unroll
  for (int tN = 0; tN < 4; tN++) {
    int u = n0 + tN * 16 + l16;
#pragma unroll
    for (int i = 0; i < 4; i++)
      agg[((size_t)b * 1024 + mbase + i) * 256 + u] = acc[tN][i];
  }
}

// ---------------- K4: Xpre[m][b][u] = (agg @ Wx)[b,m,u] + bias[u] (fp32) ----
__global__ __launch_bounds__(256, 2) void gemm_xpre(const float* __restrict__ agg,
                                                    const u16* __restrict__ Wxth,
                                                    const u16* __restrict__ Wxtl,
                                                    const float* __restrict__ bias,
                                                    float* __restrict__ Xpre) {
  __shared__ u16 Ah[64 * LDS_P], Al[64 * LDS_P];
  __shared__ u16 Bh[64 * LDS_P], Bl[64 * LDS_P];
  const int t = threadIdx.x;
  const int wave = t >> 6, lane = t & 63, quad = lane >> 4, l16 = lane & 15;
  const int r0 = blockIdx.x * 64, n0 = blockIdx.y * 64;
  f32x4 acc[4];
#pragma unroll
  for (int i = 0; i < 4; i++) acc[i] = (f32x4){0.f, 0.f, 0.f, 0.f};

  for (int kb = 0; kb < 256; kb += 64) {
#pragma unroll
    for (int cc = 0; cc < 4; cc++) {
      int c = t + cc * 256;
      int r = c >> 4, c4 = c & 15;
      f32x4 v = *(const f32x4*)(agg + (size_t)(r0 + r) * 256 + kb + c4 * 4);
      u16x4 hi, lo;
#pragma unroll
      for (int j = 0; j < 4; j++) {
        HiLo s = splitf(v[j]);
        hi[j] = s.hi; lo[j] = s.lo;
      }
      *(u16x4*)(Ah + r * LDS_P + c4 * 4) = hi;
      *(u16x4*)(Al + r * LDS_P + c4 * 4) = lo;
    }
#pragma unroll
    for (int cc = 0; cc < 2; cc++) {
      int c = t + cc * 256;
      int r = c >> 3, c8 = c & 7;
      *(u16x8*)(Bh + r * LDS_P + c8 * 8) =
          *(const u16x8*)(Wxth + (size_t)(n0 + r) * 256 + kb + c8 * 8);
      *(u16x8*)(Bl + r * LDS_P + c8 * 8) =
          *(const u16x8*)(Wxtl + (size_t)(n0 + r) * 256 + kb + c8 * 8);
    }
    __syncthreads();
#pragma unroll
    for (int kk = 0; kk < 64; kk += 32) {
      bf16x8 ah = __builtin_bit_cast(bf16x8, *(const u16x8*)(Ah + (wave * 16 + l16) * LDS_P + kk + quad * 8));
      bf16x8 al = __builtin_bit_cast(bf16x8, *(const u16x8*)(Al + (wave * 16 + l16) * LDS_P + kk + quad * 8));
#pragma unroll
      for (int tN = 0; tN < 4; tN++) {
        bf16x8 bh = __builtin_bit_cast(bf16x8, *(const u16x8*)(Bh + (tN * 16 + l16) * LDS_P + kk + quad * 8));
        bf16x8 bl = __builtin_bit_cast(bf16x8, *(const u16x8*)(Bl + (tN * 16 + l16) * LDS_P + kk + quad * 8));
        acc[tN] = __builtin_amdgcn_mfma_f32_16x16x32_bf16(ah, bh, acc[tN], 0, 0, 0);
        acc[tN] = __builtin_amdgcn_mfma_f32_16x16x32_bf16(ah, bl, acc[tN], 0, 0, 0);
        acc[tN] = __builtin_amdgcn_mfma_f32_16x16x32_bf16(al, bh, acc[tN], 0, 0, 0);
      }
    }
    __syncthreads();
  }
  const int rbase = r0 + wave * 16 + quad * 4;  // b*1024 + m
  const int bI = rbase >> 10;
#pragma unroll
  for (int tN = 0; tN < 4; tN++) {
    int u = n0 + tN * 16 + l16;
    float bu = bias[u];
#pragma unroll
    for (int i = 0; i < 4; i++) {
      int mI = (rbase + i) & 1023;
      Xpre[((size_t)mI * 8 + bI) * 256 + u] = acc[tN][i] + bu;
    }
  }
}

// ---------------- K5: sequential scan, 1 workgroup, 4 waves -----------------
// Wave w owns output cols [w*64, w*64+64) (4 n-tiles). Weights bwh[4][8]+
// bwl[4][8] = 256 regs -> AGPRs (1 wave/SIMD: ~512-reg unified budget).
// A-rows interleaved: row 2b = h_hi[batch b], row 2b+1 = h_lo[b]; per-lane
// hi/lo recombination (acc elems 2j, 2j+1). Plain b16 h-writes (R9 lesson).
__global__ __launch_bounds__(256, 1) void rnn_scan(const u16* __restrict__ Whth,
                                                   const u16* __restrict__ Whtl,
                                                   const float* __restrict__ Xpre,
                                                   float* __restrict__ out) {
  __shared__ u16 h2[2][16 * HP];
  const int t = threadIdx.x;
  const int w = t >> 6, lane = t & 63, quad = lane >> 4, l16 = lane & 15;
  const int colbase = w * 64;
  const int b0 = quad * 2;               // this lane's two batches: b0, b0+1
  int col[4];
#pragma unroll
  for (int tN = 0; tN < 4; tN++) col[tN] = colbase + tN * 16 + l16;

  // Preload Wh hi+lo fragments: 2 sets x 4 n-tiles x 8 k-blocks = 256 regs
  bf16x8 bwh[4][8], bwl[4][8];
#pragma unroll
  for (int tN = 0; tN < 4; tN++) {
    const u16* wph = Whth + (size_t)col[tN] * 256 + quad * 8;
    const u16* wpl = Whtl + (size_t)col[tN] * 256 + quad * 8;
#pragma unroll
    for (int kb = 0; kb < 8; kb++) {
      bwh[tN][kb] = __builtin_bit_cast(bf16x8, *(const u16x8*)(wph + kb * 32));
      bwl[tN][kb] = __builtin_bit_cast(bf16x8, *(const u16x8*)(wpl + kb * 32));
    }
  }
  for (int i = t; i < 2 * 16 * HP; i += 256) ((u16*)h2)[i] = 0;

  // 2-step lookahead on the additive input.
  float c0[4][2], c1[4][2], c2[4][2];
  auto loadC = [&](int m, float (&cb)[4][2]) {
    const float* xp = Xpre + (size_t)m * 2048;
#pragma unroll
    for (int tN = 0; tN < 4; tN++)
#pragma unroll
      for (int j = 0; j < 2; j++) cb[tN][j] = xp[(b0 + j) * 256 + col[tN]];
  };
  loadC(0, c0);
  loadC(1, c1);
  float pend[4][2];
  __syncthreads();

  int p = 0;
  for (int m = 0; m < 1024; m++) {
    if (m > 0) {  // fire-and-forget out-stores for step m-1
#pragma unroll
      for (int tN = 0; tN < 4; tN++)
#pragma unroll
        for (int j = 0; j < 2; j++)
          out[((size_t)(b0 + j) * 1024 + (m - 1)) * 256 + col[tN]] = pend[tN][j];
    }
    if (m < 1022) loadC(m + 2, c2);

    // Dual accumulator chains per tile (kb 0-3 vs 4-7): 8 accs total.
    f32x4 accA[4], accB[4];
#pragma unroll
    for (int i = 0; i < 4; i++) {
      accA[i] = (f32x4){0.f, 0.f, 0.f, 0.f};
      accB[i] = (f32x4){0.f, 0.f, 0.f, 0.f};
    }
#pragma unroll
    for (int kb = 0; kb < 4; kb++) {
      bf16x8 afA = __builtin_bit_cast(bf16x8,
          *(const u16x8*)(&h2[p][l16 * HP + kb * 32 + quad * 8]));
      bf16x8 afB = __builtin_bit_cast(bf16x8,
          *(const u16x8*)(&h2[p][l16 * HP + (kb + 4) * 32 + quad * 8]));
#pragma unroll
      for (int tN = 0; tN < 4; tN++) {
        accA[tN] = __builtin_amdgcn_mfma_f32_16x16x32_bf16(afA, bwh[tN][kb], accA[tN], 0, 0, 0);
        accB[tN] = __builtin_amdgcn_mfma_f32_16x16x32_bf16(afB, bwh[tN][kb + 4], accB[tN], 0, 0, 0);
      }
#pragma unroll
      for (int tN = 0; tN < 4; tN++) {
        accA[tN] = __builtin_amdgcn_mfma_f32_16x16x32_bf16(afA, bwl[tN][kb], accA[tN], 0, 0, 0);
        accB[tN] = __builtin_amdgcn_mfma_f32_16x16x32_bf16(afB, bwl[tN][kb + 4], accB[tN], 0, 0, 0);
      }
    }

    // Per-lane hi/lo recombination: C rows 2b (hi) + 2b+1 (lo) are acc
    // elements 2j and 2j+1 of this lane. No cross-lane ops.
    u16* hw = h2[1 - p];
#pragma unroll
    for (int tN = 0; tN < 4; tN++) {
#pragma unroll
      for (int j = 0; j < 2; j++) {
        float hi_part = accA[tN][2*j]     + accB[tN][2*j];
        float lo_part = accA[tN][2*j + 1] + accB[tN][2*j + 1];
        float x = (hi_part + lo_part) + c0[tN][j];
        float y = tanh_fast(x);
        HiLo s = splitf(y);
        int row = (b0 + j) * 2;  // interleaved: 2b = hi, 2b+1 = lo
        hw[row * HP + col[tN]] = s.hi;
        hw[(row + 1) * HP + col[tN]] = s.lo;
        pend[tN][j] = y;
      }
    }
#pragma unroll
    for (int tN = 0; tN < 4; tN++)
#pragma unroll
      for (int j = 0; j < 2; j++) { c0[tN][j] = c1[tN][j]; c1[tN][j] = c2[tN][j]; }
    p ^= 1;
    sync_lds_only();
  }
#pragma unroll
  for (int tN = 0; tN < 4; tN++)  // final flush (m = 1023)
#pragma unroll
    for (int j = 0; j < 2; j++)
      out[((size_t)(b0 + j) * 1024 + 1023) * 256 + col[tN]] = pend[tN][j];
}

extern "C" void kernel_launch(void* const* d_in, const int* in_sizes, int n_in,
                              void* d_out, int out_size, void* d_ws, size_t ws_size,
                              hipStream_t stream) {
  (void)in_sizes; (void)n_in; (void)out_size; (void)ws_size;
  const float* seq   = (const float*)d_in[0];  // (8,1024,256) f32
  const float* graph = (const float*)d_in[1];  // (8,1024,1024) f32
  const float* E     = (const float*)d_in[2];  // (256,256) f32
  const float* Wx    = (const float*)d_in[3];  // (256,256) f32
  const float* Wh    = (const float*)d_in[4];  // (256,256) f32
  const float* bias  = (const float*)d_in[5];  // (256,) f32
  float* out = (float*)d_out;                  // (8,1024,256) f32

  // workspace layout (bytes): ~26 MB total
  char* w = (char*)d_ws;
  float* rnorm  = (float*)(w + 0);          //  32 KB
  u16*   Eth    = (u16*)(w + 32768);        // 128 KB
  u16*   Etl    = (u16*)(w + 163840);
  u16*   Wxth   = (u16*)(w + 294912);
  u16*   Wxtl   = (u16*)(w + 425984);
  u16*   Whth   = (u16*)(w + 557056);
  u16*   Whtl   = (u16*)(w + 688128);
  u16*   betaTh = (u16*)(w + 819200);       // 4 MB [b][u][l]
  u16*   betaTl = (u16*)(w + 5013504);      // 4 MB
  float* agg    = (float*)(w + 9207808);    // 8 MB [b][m][u]
  float* Xpre   = (float*)(w + 17596416);   // 8 MB [m][b][u]

  transpose_split3<<<dim3(256, 3), 256, 0, stream>>>(E, Eth, Etl, Wx, Wxth, Wxtl, Wh, Whth, Whtl);
  rowsum_norm<<<2048, 256, 0, stream>>>(graph, rnorm);
  gemm_beta<<<dim3(128, 4), 256, 0, stream>>>(seq, Eth, Etl, rnorm, betaTh, betaTl);
  gemm_agg<<<dim3(16, 4, 8), 256, 0, stream>>>(graph, betaTh, betaTl, agg);
  gemm_xpre<<<dim3(128, 4), 256, 0, stream>>>(agg, Wxth, Wxtl, bias, Xpre);
  rnn_scan<<<1, 256, 0, stream>>>(Whth, Whtl, Xpre, out);
}

// Round 11
// 1023.959 us; speedup vs baseline: 1.5342x; 1.5342x over previous
//
#include <hip/hip_runtime.h>
#include <hip/hip_bf16.h>

// GraphRNN, fp32 I/O (reference dtypes are float32).
// beta = (seq @ E) / rowsum(graph); agg = graph^T @ beta (per batch);
// Xpre = agg @ Wx + b; then 1024-step scan h = tanh(Xpre_m + h @ Wh).
// MFMA path: fp32 operands split into bf16 hi+lo (rel err ~2^-18).
// Scan occupancy map: 4w=3315cy (R10), 8w=2515cy (R7, BEST 1073us),
// 16w=2655cy (R8). Per-CU pipes in R7: VALU ~48% (BUSIEST), MFMA ~38%,
// DS ~30% -> bookkeeping VALU (addr re-derivation, p-selects, c-shifts,
// pend movs) is the fattest target.
// R11 = R7 math, bit-identical, minus bookkeeping: m-loop unrolled x4
// (p const, LDS bases hoisted w/ imm offsets), 4 c-banks lookahead-4
// (loads post-use, no shifts), in-step out-stores (no pend; vmcnt never
// drained in-loop anyway), running += pointers for Xpre/out.

typedef unsigned short u16;
typedef unsigned int u32;
typedef __bf16 bf16_t;
typedef __bf16 bf16x8 __attribute__((ext_vector_type(8)));
typedef float f32x4 __attribute__((ext_vector_type(4)));
typedef unsigned short u16x8 __attribute__((ext_vector_type(8)));
typedef unsigned short u16x4 __attribute__((ext_vector_type(4)));

#define LDS_P 72   // LDS pitch (u16) for 64-wide tiles
#define HP    264  // h LDS pitch (u16) for the scan: 256 + 8 pad

struct HiLo { u16 hi, lo; };

__device__ __forceinline__ u16 f2bf(float f) {
  bf16_t h = (bf16_t)f;  // RNE
  return __builtin_bit_cast(u16, h);
}
__device__ __forceinline__ HiLo splitf(float v) {
  bf16_t h = (bf16_t)v;
  HiLo r;
  r.hi = __builtin_bit_cast(u16, h);
  r.lo = f2bf(v - (float)h);
  return r;
}
__device__ __forceinline__ float tanh_fast(float x) {
  float ax = fabsf(x);
  float e  = __expf(-2.0f * ax);
  float t  = __fdividef(1.0f - e, 1.0f + e);
  return copysignf(t, x);
}
// Barrier with LDS-only visibility (drains lgkmcnt, not vmcnt).
__device__ __forceinline__ void sync_lds_only() {
  __asm__ volatile("s_waitcnt lgkmcnt(0)\ns_barrier" ::: "memory");
}

// ---------------- K0: transpose + hi/lo split of E, Wx, Wh ------------------
__global__ void transpose_split3(const float* __restrict__ s0, u16* __restrict__ h0, u16* __restrict__ l0,
                                 const float* __restrict__ s1, u16* __restrict__ h1, u16* __restrict__ l1,
                                 const float* __restrict__ s2, u16* __restrict__ h2o, u16* __restrict__ l2o) {
  const int u = blockIdx.x, d = threadIdx.x;
  const float* s; u16 *dh, *dl;
  if (blockIdx.y == 0)      { s = s0; dh = h0;  dl = l0; }
  else if (blockIdx.y == 1) { s = s1; dh = h1;  dl = l1; }
  else                      { s = s2; dh = h2o; dl = l2o; }
  HiLo r = splitf(s[d * 256 + u]);
  dh[u * 256 + d] = r.hi;
  dl[u * 256 + d] = r.lo;
}

// ---------------- K1: rnorm[b,l] = 1 / max(sum_m graph[b,l,m], 1e-7) --------
__global__ void rowsum_norm(const float* __restrict__ graph, float* __restrict__ rnorm) {
  const int wave = threadIdx.x >> 6, lane = threadIdx.x & 63;
  const int row = blockIdx.x * 4 + wave;  // 0..8191
  const float* p = graph + (size_t)row * 1024 + lane * 16;
  float s = 0.f;
#pragma unroll
  for (int c = 0; c < 4; c++) {
    f32x4 v = *(const f32x4*)(p + c * 4);
#pragma unroll
    for (int j = 0; j < 4; j++) s += v[j];
  }
#pragma unroll
  for (int off = 32; off > 0; off >>= 1) s += __shfl_xor(s, off);
  if (lane == 0) rnorm[row] = 1.0f / fmaxf(s, 1e-7f);
}

// ---------------- K2: betaT[b][u][l] hi/lo = (seq@E)[b,l,u] * rnorm[b,l] ----
__global__ __launch_bounds__(256, 2) void gemm_beta(const float* __restrict__ seq,
                                                    const u16* __restrict__ Eth,
                                                    const u16* __restrict__ Etl,
                                                    const float* __restrict__ rnorm,
                                                    u16* __restrict__ betaTh,
                                                    u16* __restrict__ betaTl) {
  __shared__ u16 Ah[64 * LDS_P], Al[64 * LDS_P];
  __shared__ u16 Bh[64 * LDS_P], Bl[64 * LDS_P];
  const int t = threadIdx.x;
  const int wave = t >> 6, lane = t & 63, quad = lane >> 4, l16 = lane & 15;
  const int r0 = blockIdx.x * 64, n0 = blockIdx.y * 64;
  f32x4 acc[4];
#pragma unroll
  for (int i = 0; i < 4; i++) acc[i] = (f32x4){0.f, 0.f, 0.f, 0.f};

  for (int kb = 0; kb < 256; kb += 64) {
#pragma unroll
    for (int cc = 0; cc < 4; cc++) {
      int c = t + cc * 256;
      int r = c >> 4, c4 = c & 15;
      f32x4 v = *(const f32x4*)(seq + (size_t)(r0 + r) * 256 + kb + c4 * 4);
      u16x4 hi, lo;
#pragma unroll
      for (int j = 0; j < 4; j++) {
        HiLo s = splitf(v[j]);
        hi[j] = s.hi; lo[j] = s.lo;
      }
      *(u16x4*)(Ah + r * LDS_P + c4 * 4) = hi;
      *(u16x4*)(Al + r * LDS_P + c4 * 4) = lo;
    }
#pragma unroll
    for (int cc = 0; cc < 2; cc++) {
      int c = t + cc * 256;
      int r = c >> 3, c8 = c & 7;
      *(u16x8*)(Bh + r * LDS_P + c8 * 8) =
          *(const u16x8*)(Eth + (size_t)(n0 + r) * 256 + kb + c8 * 8);
      *(u16x8*)(Bl + r * LDS_P + c8 * 8) =
          *(const u16x8*)(Etl + (size_t)(n0 + r) * 256 + kb + c8 * 8);
    }
    __syncthreads();
#pragma unroll
    for (int kk = 0; kk < 64; kk += 32) {
      bf16x8 ah = __builtin_bit_cast(bf16x8, *(const u16x8*)(Ah + (wave * 16 + l16) * LDS_P + kk + quad * 8));
      bf16x8 al = __builtin_bit_cast(bf16x8, *(const u16x8*)(Al + (wave * 16 + l16) * LDS_P + kk + quad * 8));
#pragma unroll
      for (int tN = 0; tN < 4; tN++) {
        bf16x8 bh = __builtin_bit_cast(bf16x8, *(const u16x8*)(Bh + (tN * 16 + l16) * LDS_P + kk + quad * 8));
        bf16x8 bl = __builtin_bit_cast(bf16x8, *(const u16x8*)(Bl + (tN * 16 + l16) * LDS_P + kk + quad * 8));
        acc[tN] = __builtin_amdgcn_mfma_f32_16x16x32_bf16(ah, bh, acc[tN], 0, 0, 0);
        acc[tN] = __builtin_amdgcn_mfma_f32_16x16x32_bf16(ah, bl, acc[tN], 0, 0, 0);
        acc[tN] = __builtin_amdgcn_mfma_f32_16x16x32_bf16(al, bh, acc[tN], 0, 0, 0);
      }
    }
    __syncthreads();
  }
  const int rbase = r0 + wave * 16 + quad * 4;  // b*1024 + l, 4 consecutive l
  float rn[4];
#pragma unroll
  for (int i = 0; i < 4; i++) rn[i] = rnorm[rbase + i];
  const int bI = rbase >> 10, lI = rbase & 1023;
#pragma unroll
  for (int tN = 0; tN < 4; tN++) {
    int u = n0 + tN * 16 + l16;
    u16x4 hv, lv;
#pragma unroll
    for (int i = 0; i < 4; i++) {
      HiLo s = splitf(acc[tN][i] * rn[i]);
      hv[i] = s.hi; lv[i] = s.lo;
    }
    size_t off = ((size_t)bI << 18) + (size_t)u * 1024 + lI;
    *(u16x4*)(betaTh + off) = hv;
    *(u16x4*)(betaTl + off) = lv;
  }
}

// ---------------- K3: agg[b][m][u] = sum_l graph[b][l][m] * beta[b][l][u] ---
__global__ __launch_bounds__(256, 2) void gemm_agg(const float* __restrict__ graph,
                                                   const u16* __restrict__ betaTh,
                                                   const u16* __restrict__ betaTl,
                                                   float* __restrict__ agg) {
  __shared__ u16 Ah[64 * LDS_P], Al[64 * LDS_P];
  __shared__ u16 Bh[64 * LDS_P], Bl[64 * LDS_P];
  const int t = threadIdx.x;
  const int wave = t >> 6, lane = t & 63, quad = lane >> 4, l16 = lane & 15;
  const int m0 = blockIdx.x * 64, n0 = blockIdx.y * 64, b = blockIdx.z;
  const float* g = graph + (size_t)b * (1024 * 1024);
  const size_t bt = (size_t)b << 18;
  f32x4 acc[4];
#pragma unroll
  for (int i = 0; i < 4; i++) acc[i] = (f32x4){0.f, 0.f, 0.f, 0.f};

  for (int kb = 0; kb < 1024; kb += 64) {
#pragma unroll
    for (int cc = 0; cc < 4; cc++) {
      int c = t + cc * 256;
      int r = c >> 4, c4 = c & 15;  // r = l_local, c4 = m-chunk of 4
      f32x4 v = *(const f32x4*)(g + (size_t)(kb + r) * 1024 + m0 + c4 * 4);
#pragma unroll
      for (int j = 0; j < 4; j++) {
        HiLo s = splitf(v[j]);
        Ah[(c4 * 4 + j) * LDS_P + r] = s.hi;  // A[m][l] = graph[l][m]
        Al[(c4 * 4 + j) * LDS_P + r] = s.lo;
      }
    }
#pragma unroll
    for (int cc = 0; cc < 2; cc++) {
      int c = t + cc * 256;
      int r = c >> 3, c8 = c & 7;
      *(u16x8*)(Bh + r * LDS_P + c8 * 8) =
          *(const u16x8*)(betaTh + bt + (size_t)(n0 + r) * 1024 + kb + c8 * 8);
      *(u16x8*)(Bl + r * LDS_P + c8 * 8) =
          *(const u16x8*)(betaTl + bt + (size_t)(n0 + r) * 1024 + kb + c8 * 8);
    }
    __syncthreads();
#pragma unroll
    for (int kk = 0; kk < 64; kk += 32) {
      bf16x8 ah = __builtin_bit_cast(bf16x8, *(const u16x8*)(Ah + (wave * 16 + l16) * LDS_P + kk + quad * 8));
      bf16x8 al = __builtin_bit_cast(bf16x8, *(const u16x8*)(Al + (wave * 16 + l16) * LDS_P + kk + quad * 8));
#pragma unroll
      for (int tN = 0; tN < 4; tN++) {
        bf16x8 bh = __builtin_bit_cast(bf16x8, *(const u16x8*)(Bh + (tN * 16 + l16) * LDS_P + kk + quad * 8));
        bf16x8 bl = __builtin_bit_cast(bf16x8, *(const u16x8*)(Bl + (tN * 16 + l16) * LDS_P + kk + quad * 8));
        acc[tN] = __builtin_amdgcn_mfma_f32_16x16x32_bf16(ah, bh, acc[tN], 0, 0, 0);
        acc[tN] = __builtin_amdgcn_mfma_f32_16x16x32_bf16(ah, bl, acc[tN], 0, 0, 0);
        acc[tN] = __builtin_amdgcn_mfma_f32_16x16x32_bf16(al, bh, acc[tN], 0, 0, 0);
      }
    }
    __syncthreads();
  }
  const int mbase = m0 + wave * 16 + quad * 4;
#pragma unroll
  for (int tN = 0; tN < 4; tN++) {
    int u = n0 + tN * 16 + l16;
#pragma unroll
    for (int i = 0; i < 4; i++)
      agg[((size_t)b * 1024 + mbase + i) * 256 + u] = acc[tN][i];
  }
}

// ---------------- K4: Xpre[m][b][u] = (agg @ Wx)[b,m,u] + bias[u] (fp32) ----
__global__ __launch_bounds__(256, 2) void gemm_xpre(const float* __restrict__ agg,
                                                    const u16* __restrict__ Wxth,
                                                    const u16* __restrict__ Wxtl,
                                                    const float* __restrict__ bias,
                                                    float* __restrict__ Xpre) {
  __shared__ u16 Ah[64 * LDS_P], Al[64 * LDS_P];
  __shared__ u16 Bh[64 * LDS_P], Bl[64 * LDS_P];
  const int t = threadIdx.x;
  const int wave = t >> 6, lane = t & 63, quad = lane >> 4, l16 = lane & 15;
  const int r0 = blockIdx.x * 64, n0 = blockIdx.y * 64;
  f32x4 acc[4];
#pragma unroll
  for (int i = 0; i < 4; i++) acc[i] = (f32x4){0.f, 0.f, 0.f, 0.f};

  for (int kb = 0; kb < 256; kb += 64) {
#pragma unroll
    for (int cc = 0; cc < 4; cc++) {
      int c = t + cc * 256;
      int r = c >> 4, c4 = c & 15;
      f32x4 v = *(const f32x4*)(agg + (size_t)(r0 + r) * 256 + kb + c4 * 4);
      u16x4 hi, lo;
#pragma unroll
      for (int j = 0; j < 4; j++) {
        HiLo s = splitf(v[j]);
        hi[j] = s.hi; lo[j] = s.lo;
      }
      *(u16x4*)(Ah + r * LDS_P + c4 * 4) = hi;
      *(u16x4*)(Al + r * LDS_P + c4 * 4) = lo;
    }
#pragma unroll
    for (int cc = 0; cc < 2; cc++) {
      int c = t + cc * 256;
      int r = c >> 3, c8 = c & 7;
      *(u16x8*)(Bh + r * LDS_P + c8 * 8) =
          *(const u16x8*)(Wxth + (size_t)(n0 + r) * 256 + kb + c8 * 8);
      *(u16x8*)(Bl + r * LDS_P + c8 * 8) =
          *(const u16x8*)(Wxtl + (size_t)(n0 + r) * 256 + kb + c8 * 8);
    }
    __syncthreads();
#pragma unroll
    for (int kk = 0; kk < 64; kk += 32) {
      bf16x8 ah = __builtin_bit_cast(bf16x8, *(const u16x8*)(Ah + (wave * 16 + l16) * LDS_P + kk + quad * 8));
      bf16x8 al = __builtin_bit_cast(bf16x8, *(const u16x8*)(Al + (wave * 16 + l16) * LDS_P + kk + quad * 8));
#pragma unroll
      for (int tN = 0; tN < 4; tN++) {
        bf16x8 bh = __builtin_bit_cast(bf16x8, *(const u16x8*)(Bh + (tN * 16 + l16) * LDS_P + kk + quad * 8));
        bf16x8 bl = __builtin_bit_cast(bf16x8, *(const u16x8*)(Bl + (tN * 16 + l16) * LDS_P + kk + quad * 8));
        acc[tN] = __builtin_amdgcn_mfma_f32_16x16x32_bf16(ah, bh, acc[tN], 0, 0, 0);
        acc[tN] = __builtin_amdgcn_mfma_f32_16x16x32_bf16(ah, bl, acc[tN], 0, 0, 0);
        acc[tN] = __builtin_amdgcn_mfma_f32_16x16x32_bf16(al, bh, acc[tN], 0, 0, 0);
      }
    }
    __syncthreads();
  }
  const int rbase = r0 + wave * 16 + quad * 4;  // b*1024 + m
  const int bI = rbase >> 10;
#pragma unroll
  for (int tN = 0; tN < 4; tN++) {
    int u = n0 + tN * 16 + l16;
    float bu = bias[u];
#pragma unroll
    for (int i = 0; i < 4; i++) {
      int mI = (rbase + i) & 1023;
      Xpre[((size_t)mI * 8 + bI) * 256 + u] = acc[tN][i] + bu;
    }
  }
}

// ---------------- K5: sequential scan, 1 workgroup, 8 waves (R7 math) -------
// Wave w owns output cols [w*32, w*32+32). A-rows interleaved: row 2b =
// h_hi[batch b], row 2b+1 = h_lo[b]; per-lane hi/lo recombination.
// R11: m-loop unrolled x4 (p const), 4 c-banks lookahead-4, in-step
// out-stores, running pointers. Bit-identical math to R7.
__global__ __launch_bounds__(512, 2) void rnn_scan(const u16* __restrict__ Whth,
                                                   const u16* __restrict__ Whtl,
                                                   const float* __restrict__ Xpre,
                                                   float* __restrict__ out) {
  __shared__ u16 h2[2][16 * HP];
  const int t = threadIdx.x;
  const int w = t >> 6, lane = t & 63, quad = lane >> 4, l16 = lane & 15;
  const int colbase = w * 32;
  const int b0 = quad * 2;               // this lane's two batches: b0, b0+1
  int col[2];
  col[0] = colbase + l16;
  col[1] = colbase + 16 + l16;

  // Preload Wh hi+lo fragments: 2 sets x 2 n-tiles x 8 k-blocks (AGPRs)
  bf16x8 bwh[2][8], bwl[2][8];
#pragma unroll
  for (int tN = 0; tN < 2; tN++) {
    const u16* wph = Whth + (size_t)(colbase + tN * 16 + l16) * 256 + quad * 8;
    const u16* wpl = Whtl + (size_t)(colbase + tN * 16 + l16) * 256 + quad * 8;
#pragma unroll
    for (int kb = 0; kb < 8; kb++) {
      bwh[tN][kb] = __builtin_bit_cast(bf16x8, *(const u16x8*)(wph + kb * 32));
      bwl[tN][kb] = __builtin_bit_cast(bf16x8, *(const u16x8*)(wpl + kb * 32));
    }
  }
  for (int i = t; i < 2 * 16 * HP; i += 512) ((u16*)h2)[i] = 0;

  // c banks 0..3 hold the additive input for steps m4+0..m4+3 (lookahead 4).
  float cb[4][2][2];
#pragma unroll
  for (int k = 0; k < 4; k++) {
    const float* xp = Xpre + (size_t)k * 2048;
#pragma unroll
    for (int tt = 0; tt < 2; tt++)
#pragma unroll
      for (int j = 0; j < 2; j++) cb[k][tt][j] = xp[(b0 + j) * 256 + col[tt]];
  }
  // Running pointers (advance by constants; no per-step re-derivation).
  const float* ldp0 = Xpre + 4 * 2048 + (b0 + 0) * 256;
  const float* ldp1 = Xpre + 4 * 2048 + (b0 + 1) * 256;
  float* outp0 = out + (size_t)(b0 + 0) * 262144;
  float* outp1 = out + (size_t)(b0 + 1) * 262144;
  // Hoisted LDS bases (read: per-lane fragment base; write: buffer base).
  const u16* rb0 = &h2[0][l16 * HP + quad * 8];
  const u16* rb1 = &h2[1][l16 * HP + quad * 8];
  u16* wb0 = &h2[0][0];
  u16* wb1 = &h2[1][0];
  __syncthreads();

  for (int m4 = 0; m4 < 1024; m4 += 4) {
#pragma unroll
    for (int k = 0; k < 4; k++) {
      const int p = k & 1;                       // compile-time in unrolled body
      const u16* rb = p ? rb1 : rb0;
      u16* hw = p ? wb0 : wb1;                   // write the other buffer

      f32x4 a0a = {0.f,0.f,0.f,0.f}, a0b = {0.f,0.f,0.f,0.f};
      f32x4 a1a = {0.f,0.f,0.f,0.f}, a1b = {0.f,0.f,0.f,0.f};
#pragma unroll
      for (int kb = 0; kb < 4; kb++) {
        bf16x8 afA = __builtin_bit_cast(bf16x8, *(const u16x8*)(rb + kb * 32));
        bf16x8 afB = __builtin_bit_cast(bf16x8, *(const u16x8*)(rb + (kb + 4) * 32));
        a0a = __builtin_amdgcn_mfma_f32_16x16x32_bf16(afA, bwh[0][kb], a0a, 0, 0, 0);
        a1a = __builtin_amdgcn_mfma_f32_16x16x32_bf16(afA, bwh[1][kb], a1a, 0, 0, 0);
        a0b = __builtin_amdgcn_mfma_f32_16x16x32_bf16(afB, bwh[0][kb + 4], a0b, 0, 0, 0);
        a1b = __builtin_amdgcn_mfma_f32_16x16x32_bf16(afB, bwh[1][kb + 4], a1b, 0, 0, 0);
        a0a = __builtin_amdgcn_mfma_f32_16x16x32_bf16(afA, bwl[0][kb], a0a, 0, 0, 0);
        a1a = __builtin_amdgcn_mfma_f32_16x16x32_bf16(afA, bwl[1][kb], a1a, 0, 0, 0);
        a0b = __builtin_amdgcn_mfma_f32_16x16x32_bf16(afB, bwl[0][kb + 4], a0b, 0, 0, 0);
        a1b = __builtin_amdgcn_mfma_f32_16x16x32_bf16(afB, bwl[1][kb + 4], a1b, 0, 0, 0);
      }

      // Epilogue: per-lane hi/lo recombine (acc elems 2j, 2j+1), tanh, split,
      // h-write (b16, R7 layout) + in-step global out-store (fire-and-forget).
#pragma unroll
      for (int tt = 0; tt < 2; tt++) {
#pragma unroll
        for (int j = 0; j < 2; j++) {
          float hi_part = (tt ? a1a[2*j]     : a0a[2*j])     + (tt ? a1b[2*j]     : a0b[2*j]);
          float lo_part = (tt ? a1a[2*j + 1] : a0a[2*j + 1]) + (tt ? a1b[2*j + 1] : a0b[2*j + 1]);
          float x = (hi_part + lo_part) + cb[k][tt][j];
          float y = tanh_fast(x);
          HiLo s = splitf(y);
          int row = (b0 + j) * 2;  // interleaved: 2b = hi, 2b+1 = lo
          hw[row * HP + col[tt]] = s.hi;
          hw[(row + 1) * HP + col[tt]] = s.lo;
          (j ? outp1 : outp0)[col[tt]] = y;
        }
      }
      outp0 += 256; outp1 += 256;

      // Prefetch c for step m+4 into the bank just consumed.
      if (m4 <= 1019 - k) {
#pragma unroll
        for (int tt = 0; tt < 2; tt++) {
          cb[k][tt][0] = ldp0[col[tt]];
          cb[k][tt][1] = ldp1[col[tt]];
        }
        ldp0 += 2048; ldp1 += 2048;
      }
      sync_lds_only();
    }
  }
}

extern "C" void kernel_launch(void* const* d_in, const int* in_sizes, int n_in,
                              void* d_out, int out_size, void* d_ws, size_t ws_size,
                              hipStream_t stream) {
  (void)in_sizes; (void)n_in; (void)out_size; (void)ws_size;
  const float* seq   = (const float*)d_in[0];  // (8,1024,256) f32
  const float* graph = (const float*)d_in[1];  // (8,1024,1024) f32
  const float* E     = (const float*)d_in[2];  // (256,256) f32
  const float* Wx    = (const float*)d_in[3];  // (256,256) f32
  const float* Wh    = (const float*)d_in[4];  // (256,256) f32
  const float* bias  = (const float*)d_in[5];  // (256,) f32
  float* out = (float*)d_out;                  // (8,1024,256) f32

  // workspace layout (bytes): ~26 MB total
  char* w = (char*)d_ws;
  float* rnorm  = (float*)(w + 0);          //  32 KB
  u16*   Eth    = (u16*)(w + 32768);        // 128 KB
  u16*   Etl    = (u16*)(w + 163840);
  u16*   Wxth   = (u16*)(w + 294912);
  u16*   Wxtl   = (u16*)(w + 425984);
  u16*   Whth   = (u16*)(w + 557056);
  u16*   Whtl   = (u16*)(w + 688128);
  u16*   betaTh = (u16*)(w + 819200);       // 4 MB [b][u][l]
  u16*   betaTl = (u16*)(w + 5013504);      // 4 MB
  float* agg    = (float*)(w + 9207808);    // 8 MB [b][m][u]
  float* Xpre   = (float*)(w + 17596416);   // 8 MB [m][b][u]

  transpose_split3<<<dim3(256, 3), 256, 0, stream>>>(E, Eth, Etl, Wx, Wxth, Wxtl, Wh, Whth, Whtl);
  rowsum_norm<<<2048, 256, 0, stream>>>(graph, rnorm);
  gemm_beta<<<dim3(128, 4), 256, 0, stream>>>(seq, Eth, Etl, rnorm, betaTh, betaTl);
  gemm_agg<<<dim3(16, 4, 8), 256, 0, stream>>>(graph, betaTh, betaTl, agg);
  gemm_xpre<<<dim3(128, 4), 256, 0, stream>>>(agg, Wxth, Wxtl, bias, Xpre);
  rnn_scan<<<1, 512, 0, stream>>>(Whth, Whtl, Xpre, out);
}